// Round 9
// baseline (331.703 us; speedup 1.0000x reference)
//
#include <hip/hip_runtime.h>
#include <hip/hip_bf16.h>

typedef unsigned short ushort_t;
typedef __attribute__((ext_vector_type(8))) short short8;
typedef __attribute__((ext_vector_type(4))) float f32x4;

#define HIDDEN 256
#define N_NODES 50000
#define BM 64
#define LDSROW 512   // bf16 row = 512B; XOR-swizzled 16B slots
#define NTOT (2 * N_NODES)                    // concatenated dst|src counters

__device__ __forceinline__ unsigned int f2bf(float f) {
    union { float f; unsigned int i; } v; v.f = f;
    return (v.i + 0x7fffu + ((v.i >> 16) & 1u)) >> 16;
}
__device__ __forceinline__ float bf2f(unsigned int u) {
    union { unsigned int i; float f; } v; v.i = u << 16; return v.f;
}

// ws layout (bytes)
#define OFF_P      0u                         // 300000*256 bf16 = 153,600,000
#define OFF_WF     153600000u                 // 65536 bf16 fragment-major
#define OFF_CNT    153731072u                 // int[100000]
#define OFF_OFFS   154131072u                 // int[100001]
#define OFF_CUR    154531076u                 // int[100000]
#define OFF_ELIST  154931076u                 // int[600000]
#define OFF_BSUM   157331076u                 // int[1024]

#define SCAN_NBLK ((NTOT + 255) / 256)        // 391

// Kernel 0: pack W fp32 -> bf16 fragment-major.
// Wf[(((g*8)+kk)*64 + lane)*8 + t] = W[g*16 + (lane&15)][kk*32 + (lane>>4)*8 + t]
__global__ void convert_w_frag(const float* __restrict__ W, ushort_t* __restrict__ Wf, int n) {
    int i = blockIdx.x * blockDim.x + threadIdx.x;
    if (i >= n) return;
    const int t    = i & 7;
    const int lane = (i >> 3) & 63;
    const int kk   = (i >> 9) & 7;
    const int g    = i >> 12;
    const int j = g * 16 + (lane & 15);
    const int k = kk * 32 + ((lane >> 4) & 3) * 8 + t;
    Wf[i] = (ushort_t)f2bf(W[j * HIDDEN + k]);
}

// zero int buffer (replaces hipMemsetAsync)
__global__ void zero_i32(int* __restrict__ p, int n) {
    int i = blockIdx.x * blockDim.x + threadIdx.x;
    if (i < n) p[i] = 0;
}

// count both dst (cnt[0..N)) and src (cnt[N..2N)) histograms
__global__ void count_both(const int* __restrict__ src, const int* __restrict__ dst,
                           int* __restrict__ cnt, int n) {
    int i = blockIdx.x * blockDim.x + threadIdx.x;
    if (i < n) {
        atomicAdd(&cnt[dst[i]], 1);
        atomicAdd(&cnt[N_NODES + src[i]], 1);
    }
}

// per-256-block exclusive scan, block sums out
__global__ __launch_bounds__(256)
void block_scan(const int* __restrict__ cnt, int* __restrict__ offs,
                int* __restrict__ bsum) {
    __shared__ int sh[256];
    const int t = threadIdx.x;
    const int idx = blockIdx.x * 256 + t;
    int v = (idx < NTOT) ? cnt[idx] : 0;
    sh[t] = v;
    __syncthreads();
    for (int off = 1; off < 256; off <<= 1) {
        int x = (t >= off) ? sh[t - off] : 0;
        __syncthreads();
        sh[t] += x;
        __syncthreads();
    }
    if (idx < NTOT) offs[idx] = sh[t] - v;
    if (t == 255) bsum[blockIdx.x] = sh[255];
}

// exclusive scan of block sums (single 1024-thread block, nb <= 1024)
__global__ __launch_bounds__(1024)
void scan_bsum(int* __restrict__ bsum, int nb) {
    __shared__ int sh[1024];
    const int t = threadIdx.x;
    int v = (t < nb) ? bsum[t] : 0;
    sh[t] = v;
    __syncthreads();
    for (int off = 1; off < 1024; off <<= 1) {
        int x = (t >= off) ? sh[t - off] : 0;
        __syncthreads();
        sh[t] += x;
        __syncthreads();
    }
    if (t < nb) bsum[t] = sh[t] - v;
}

// offs += base; cur = offs; offs[NTOT] = 2*n_edges
__global__ __launch_bounds__(256)
void add_base(int* __restrict__ offs, const int* __restrict__ bsum,
              int* __restrict__ cur, int n_edges) {
    const int idx = blockIdx.x * 256 + threadIdx.x;
    if (idx < NTOT) {
        int o = offs[idx] + bsum[idx >> 8];
        offs[idx] = o;
        cur[idx] = o;
    }
    if (idx == 0) offs[NTOT] = 2 * n_edges;
}

// bucket edge ids by destination AND by source (concatenated elist)
__global__ void fill_both(const int* __restrict__ src, const int* __restrict__ dst,
                          int* __restrict__ cur, int* __restrict__ elist, int n) {
    int i = blockIdx.x * blockDim.x + threadIdx.x;
    if (i < n) {
        int pd = atomicAdd(&cur[dst[i]], 1);
        elist[pd] = i;
        int ps = atomicAdd(&cur[N_NODES + src[i]], 1);
        elist[ps] = i;
    }
}

// Kernel P: P = relu(E) @ W.T  (bf16 out). Dense sequential rows, LDS-staged,
// swapped MFMA operands (lane holds edge row l15 x 4 consecutive out cols).
__global__ __launch_bounds__(256, 4)
void gemm_P(const float* __restrict__ E,
            const ushort_t* __restrict__ Wf,
            unsigned int* __restrict__ P, int n_edges) {
    __shared__ __align__(16) unsigned char lds[BM * LDSROW];
    const int tid = threadIdx.x;
    const int row0 = blockIdx.x * BM;
    const int lane = tid & 63;
    const int wid  = tid >> 6;

    // stage A = bf16(relu(E rows)), wave-per-row: lane l loads 16B at l*16.
    {
        const int wrow = wid * 16;
#pragma unroll
        for (int rr = 0; rr < 16; rr += 4) {
            float4 ev[4];
            const int rbase = wrow + rr;
#pragma unroll
            for (int i = 0; i < 4; ++i) {
                int gr = row0 + rbase + i;
                int grc = (gr < n_edges) ? gr : (n_edges - 1);
                ev[i] = *(const float4*)(E + (size_t)grc * HIDDEN + lane * 4);
            }
#pragma unroll
            for (int i = 0; i < 4; ++i) {
                const int r = rbase + i;
                uint2 o;
                o.x = f2bf(fmaxf(ev[i].x, 0.f)) | (f2bf(fmaxf(ev[i].y, 0.f)) << 16);
                o.y = f2bf(fmaxf(ev[i].z, 0.f)) | (f2bf(fmaxf(ev[i].w, 0.f)) << 16);
                const int slot = (lane >> 1) ^ (r & 7);
                *(uint2*)(lds + r * LDSROW + slot * 16 + (lane & 1) * 8) = o;
            }
        }
    }
    __syncthreads();

    const int l15   = lane & 15;
    const int hi16  = lane >> 4;
    const int wcol0 = wid * 64;
    const int r7l   = l15 & 7;

    f32x4 acc[4][4];
#pragma unroll
    for (int m = 0; m < 4; ++m)
#pragma unroll
        for (int n = 0; n < 4; ++n)
            acc[m][n] = (f32x4){0.f, 0.f, 0.f, 0.f};

#pragma unroll 2
    for (int kk = 0; kk < 8; ++kk) {
        const int slotbyte = ((kk * 4 + hi16) ^ r7l) * 16;
        short8 a[4], bfr[4];
#pragma unroll
        for (int m = 0; m < 4; ++m)
            a[m] = *(const short8*)(lds + (m * 16 + l15) * LDSROW + slotbyte);
#pragma unroll
        for (int n = 0; n < 4; ++n)
            bfr[n] = *(const short8*)(Wf + (size_t)((((wid * 4 + n) * 8 + kk) * 64 + lane) << 3));
#pragma unroll
        for (int m = 0; m < 4; ++m)
#pragma unroll
            for (int n = 0; n < 4; ++n)
                acc[m][n] = __builtin_amdgcn_mfma_f32_16x16x32_bf16(bfr[n], a[m], acc[m][n], 0, 0, 0);
    }

    // epilogue: store P bf16. lane: row=l15(+16m), cols cb..cb+3 -> uint2.
#pragma unroll
    for (int m = 0; m < 4; ++m) {
        const int row = row0 + m * 16 + l15;
        if (row < n_edges) {
            unsigned int* prow = P + (size_t)row * (HIDDEN / 2);
#pragma unroll
            for (int n = 0; n < 4; ++n) {
                const int cb = wcol0 + n * 16 + hi16 * 4;
                uint2 o;
                o.x = f2bf(acc[m][n][0]) | (f2bf(acc[m][n][1]) << 16);
                o.y = f2bf(acc[m][n][2]) | (f2bf(acc[m][n][3]) << 16);
                *(uint2*)(prow + (cb >> 1)) = o;
            }
        }
    }
}

// Kernel QO: per node v: Q_v = sum_{e in dst-bucket} P[e] (fp32 regs), then
// for each e in src-bucket: out[e] = Q_v - P[rev[e]] + b. Wave per node,
// lane owns 4 consecutive cols. P reads are L3-resident; out writes 1KB/row.
__global__ __launch_bounds__(256)
void node_fused(const unsigned int* __restrict__ P,
                const int* __restrict__ offs,
                const int* __restrict__ elist,
                const int* __restrict__ rev,
                const float* __restrict__ bias,
                float* __restrict__ out) {
    const int node = blockIdx.x * 4 + (threadIdx.x >> 6);
    const int lane = threadIdx.x & 63;
    if (node >= N_NODES) return;

    // --- Q_v over dst bucket
    const int d0 = offs[node];
    const int d1 = offs[node + 1];
    float q0 = 0.f, q1 = 0.f, q2 = 0.f, q3 = 0.f;
    int j = d0;
    for (; j + 4 <= d1; j += 4) {
        const int e0 = elist[j], e1 = elist[j + 1], e2 = elist[j + 2], e3 = elist[j + 3];
        uint2 p0 = *(const uint2*)(P + (size_t)e0 * (HIDDEN / 2) + lane * 2);
        uint2 p1 = *(const uint2*)(P + (size_t)e1 * (HIDDEN / 2) + lane * 2);
        uint2 p2 = *(const uint2*)(P + (size_t)e2 * (HIDDEN / 2) + lane * 2);
        uint2 p3 = *(const uint2*)(P + (size_t)e3 * (HIDDEN / 2) + lane * 2);
        q0 += bf2f(p0.x & 0xffffu) + bf2f(p1.x & 0xffffu) + bf2f(p2.x & 0xffffu) + bf2f(p3.x & 0xffffu);
        q1 += bf2f(p0.x >> 16)     + bf2f(p1.x >> 16)     + bf2f(p2.x >> 16)     + bf2f(p3.x >> 16);
        q2 += bf2f(p0.y & 0xffffu) + bf2f(p1.y & 0xffffu) + bf2f(p2.y & 0xffffu) + bf2f(p3.y & 0xffffu);
        q3 += bf2f(p0.y >> 16)     + bf2f(p1.y >> 16)     + bf2f(p2.y >> 16)     + bf2f(p3.y >> 16);
    }
    for (; j < d1; ++j) {
        uint2 p = *(const uint2*)(P + (size_t)elist[j] * (HIDDEN / 2) + lane * 2);
        q0 += bf2f(p.x & 0xffffu);
        q1 += bf2f(p.x >> 16);
        q2 += bf2f(p.y & 0xffffu);
        q3 += bf2f(p.y >> 16);
    }
    float4 bv = *(const float4*)(bias + lane * 4);
    q0 += bv.x; q1 += bv.y; q2 += bv.z; q3 += bv.w;

    // --- emit out rows over src bucket
    const int s0 = offs[N_NODES + node];
    const int s1 = offs[N_NODES + node + 1];
    j = s0;
    for (; j + 2 <= s1; j += 2) {
        const int e0 = elist[j], e1 = elist[j + 1];
        const int r0 = rev[e0], r1 = rev[e1];
        uint2 p0 = *(const uint2*)(P + (size_t)r0 * (HIDDEN / 2) + lane * 2);
        uint2 p1 = *(const uint2*)(P + (size_t)r1 * (HIDDEN / 2) + lane * 2);
        float4 o0, o1;
        o0.x = q0 - bf2f(p0.x & 0xffffu);
        o0.y = q1 - bf2f(p0.x >> 16);
        o0.z = q2 - bf2f(p0.y & 0xffffu);
        o0.w = q3 - bf2f(p0.y >> 16);
        o1.x = q0 - bf2f(p1.x & 0xffffu);
        o1.y = q1 - bf2f(p1.x >> 16);
        o1.z = q2 - bf2f(p1.y & 0xffffu);
        o1.w = q3 - bf2f(p1.y >> 16);
        *(float4*)(out + (size_t)e0 * HIDDEN + lane * 4) = o0;
        *(float4*)(out + (size_t)e1 * HIDDEN + lane * 4) = o1;
    }
    for (; j < s1; ++j) {
        const int e = elist[j];
        const int r = rev[e];
        uint2 p = *(const uint2*)(P + (size_t)r * (HIDDEN / 2) + lane * 2);
        float4 o;
        o.x = q0 - bf2f(p.x & 0xffffu);
        o.y = q1 - bf2f(p.x >> 16);
        o.z = q2 - bf2f(p.y & 0xffffu);
        o.w = q3 - bf2f(p.y >> 16);
        *(float4*)(out + (size_t)e * HIDDEN + lane * 4) = o;
    }
}

extern "C" void kernel_launch(void* const* d_in, const int* in_sizes, int n_in,
                              void* d_out, int out_size, void* d_ws, size_t ws_size,
                              hipStream_t stream) {
    const float* E    = (const float*)d_in[0];
    const int*   ei   = (const int*)d_in[1];
    const int*   rev  = (const int*)d_in[2];
    const float* W    = (const float*)d_in[3];
    const float* bias = (const float*)d_in[4];
    float* out = (float*)d_out;
    const int n_edges = in_sizes[2];
    const int* srcI = ei;              // edge_index[0]
    const int* dstI = ei + n_edges;    // edge_index[1]

    char* ws = (char*)d_ws;
    unsigned int* P    = (unsigned int*)(ws + OFF_P);
    ushort_t*     Wf   = (ushort_t*)(ws + OFF_WF);
    int*          cnt  = (int*)(ws + OFF_CNT);
    int*          offs = (int*)(ws + OFF_OFFS);
    int*          cur  = (int*)(ws + OFF_CUR);
    int*          elst = (int*)(ws + OFF_ELIST);
    int*          bsum = (int*)(ws + OFF_BSUM);

    zero_i32<<<SCAN_NBLK, 256, 0, stream>>>(cnt, NTOT);
    convert_w_frag<<<(HIDDEN * HIDDEN + 255) / 256, 256, 0, stream>>>(W, Wf, HIDDEN * HIDDEN);

    count_both<<<(n_edges + 255) / 256, 256, 0, stream>>>(srcI, dstI, cnt, n_edges);
    block_scan<<<SCAN_NBLK, 256, 0, stream>>>(cnt, offs, bsum);
    scan_bsum<<<1, 1024, 0, stream>>>(bsum, SCAN_NBLK);
    add_base<<<SCAN_NBLK, 256, 0, stream>>>(offs, bsum, cur, n_edges);
    fill_both<<<(n_edges + 255) / 256, 256, 0, stream>>>(srcI, dstI, cur, elst, n_edges);

    const int nblk = (n_edges + BM - 1) / BM;
    gemm_P<<<nblk, 256, 0, stream>>>(E, Wf, P, n_edges);

    node_fused<<<(N_NODES + 3) / 4, 256, 0, stream>>>(P, offs, elst, rev, bias, out);
}